// Round 14
// baseline (190.813 us; speedup 1.0000x reference)
//
#include <hip/hip_runtime.h>

#define GN   1024
#define GNN  (GN * GN)
#define GP   16
#define NOUT 127          // ys[1:] = T_1 .. T_127
#define TI   64           // output tile side
#define KH   16           // halo depth = fused steps per launch
#define SZI  96           // region side (TI + 2*KH)
#define NRB  24           // row-blocks  (SZI/4)
#define NCB  24           // col-blocks  (SZI/4)
#define NTHR 576          // NRB*NCB threads, 9 waves
#define RST  100          // row-plane stride (floats), 4-aligned
#define AXB  (NRB * 2 * RST)            // aux base within plane = 4800
#define AXS  ((NCB + 1) * RST)          // one aux side = 2500
#define PLN  (AXB + 2 * AXS)            // plane floats = 9800 (39.2 KB)

typedef float f2 __attribute__((ext_vector_type(2)));

// ---- VOP3P packed-f32 primitives (r13, verified bitwise-exact)
__device__ __forceinline__ f2 pk_add(f2 a, f2 b) {
    f2 d; asm("v_pk_add_f32 %0, %1, %2" : "=v"(d) : "v"(a), "v"(b)); return d;
}
__device__ __forceinline__ f2 pk_sub(f2 a, f2 b) {   // a - b
    f2 d; asm("v_pk_add_f32 %0, %1, %2 neg_lo:[0,1] neg_hi:[0,1]"
              : "=v"(d) : "v"(a), "v"(b)); return d;
}
__device__ __forceinline__ f2 pk_mul(f2 a, f2 b) {
    f2 d; asm("v_pk_mul_f32 %0, %1, %2" : "=v"(d) : "v"(a), "v"(b)); return d;
}
__device__ __forceinline__ f2 pk_fma(f2 a, f2 b, f2 c) {   // a*b + c
    f2 d; asm("v_pk_fma_f32 %0, %1, %2, %3"
              : "=v"(d) : "v"(a), "v"(b), "v"(c)); return d;
}

// ---- DPP wave shifts (gfx9 ctrl: wave_shl:1 = 0x130, wave_shr:1 = 0x138).
// shr1: lane n <- lane n-1 (SL direction); shl1: lane n <- lane n+1 (SR).
__device__ __forceinline__ float dpp_shr1(float x) {
    int r = __builtin_amdgcn_mov_dpp(__float_as_int(x), 0x138, 0xf, 0xf, false);
    return __int_as_float(r);
}
__device__ __forceinline__ float dpp_shl1(float x) {
    int r = __builtin_amdgcn_mov_dpp(__float_as_int(x), 0x130, 0xf, 0xf, false);
    return __int_as_float(r);
}

// Exact fp32 constants: DT/dx^2 = 1e-7*1023^2 = 0.1046529, DT/(2dx) = 5.115e-5

__device__ __forceinline__ void coord16(int t, int& c0, int& c1, float& w) {
    double c = (double)t * (15.0 / 1023.0);
    c0 = (int)c;
    c1 = c0 + 1 > 15 ? 15 : c0 + 1;
    w  = (float)(c - (double)c0);
}

__device__ __forceinline__ float bilin16(const float* __restrict__ m,
                                         int i0, int i1, float wi,
                                         int j0, int j1, float wj) {
    float m00 = m[i0 * GP + j0];
    float m10 = m[i1 * GP + j0];
    float m01 = m[i0 * GP + j1];
    float m11 = m[i1 * GP + j1];
    float r0 = m00 * (1.0f - wi) + m10 * wi;
    float r1 = m01 * (1.0f - wi) + m11 * wi;
    return r0 * (1.0f - wj) + r1 * wj;
}

// Packed pair stencil — bitwise identical to scalar cellv (k2 pre-negated).
__device__ __forceinline__ f2 pairv(f2 C, f2 L, f2 R, f2 U, f2 D,
                                    f2 a2, f2 nk2, f2 m4) {
    f2 s   = pk_add(pk_sub(D, U), pk_sub(R, L));
    f2 lap = pk_fma(m4, C, pk_add(pk_add(U, D), pk_add(L, R)));
    f2 cs  = pk_mul(C, s);
    return pk_fma(a2, lap, pk_fma(nk2, cs, C));
}

// LDS barrier (memory clobber; r11 proved vmcnt-drain is perf-neutral here).
__device__ __forceinline__ void lds_barrier() {
    __builtin_amdgcn_sched_barrier(0);
    asm volatile("s_waitcnt lgkmcnt(0)" ::: "memory");
    __builtin_amdgcn_s_barrier();
    __builtin_amdgcn_sched_barrier(0);
}

// Clamp-baked, pre-scaled coefficient maps.
__global__ __launch_bounds__(256)
void resize_maps_kernel(const float* __restrict__ alpha,
                        const float* __restrict__ kappa,
                        float* __restrict__ a2map,
                        float* __restrict__ k2map) {
    int idx = blockIdx.x * 256 + threadIdx.x;
    if (idx >= GNN) return;
    int i = idx >> 10;
    int j = idx & (GN - 1);
    int ci = i < 1 ? 1 : (i > GN - 2 ? GN - 2 : i);
    int cj = j < 1 ? 1 : (j > GN - 2 ? GN - 2 : j);
    int i0, i1, j0, j1; float wi, wj;
    coord16(ci, i0, i1, wi);
    coord16(cj, j0, j1, wj);
    a2map[idx] = bilin16(alpha, i0, i1, wi, j0, j1, wj) * 0.1046529f;
    k2map[idx] = bilin16(kappa, i0, i1, wi, j0, j1, wj) * 5.115e-5f;
}

// Temporal-blocked stepper (verified rounds 4-13). Horizontal L/R exchange
// now via DPP wave shifts: left neighbor = tid-1 = lane-1 within the wave
// everywhere except wave-boundary lanes; those use the (retained) aux-column
// LDS path, exec-masked to lane 0 / lane 63. Cross-wave crossings at tids
// 192/384 are isl-replica threads (cb==0) which never consume SL. The
// shrinking row window guarantees aux producers were active one step before
// their consumers. Row writes and global stores merged back to b128.
template <bool USE_WS>
__global__ __launch_bounds__(NTHR)
void fused_steps_kernel(const float* __restrict__ srcp,
                        const float* __restrict__ Aarg,   // a2map or alpha
                        const float* __restrict__ Karg,   // k2map or kappa
                        float* __restrict__ out,
                        int base)
{
    __shared__ float lds[2][PLN];   // 2 x 39.2 KB

    const int tid  = threadIdx.x;
    const int lane = tid & 63;
    const int rb  = tid / NCB;
    const int cb  = tid - rb * NCB;
    const int r0  = rb * 4;
    const int c4  = cb * 4;

    const int gi0 = blockIdx.y * TI;
    const int gj0 = blockIdx.x * TI;
    int oi = gi0 - KH; oi = oi < 0 ? 0 : (oi > GN - SZI ? GN - SZI : oi);
    int oj = gj0 - KH; oj = oj < 0 ? 0 : (oj > GN - SZI ? GN - SZI : oj);
    const int di = gi0 - oi;           // 0, 16, or 32
    const int dj = gj0 - oj;

    const bool istop = (rb == 0), isbot = (rb == NRB - 1);
    const bool isl   = (cb == 0), isr   = (cb == NCB - 1);
    const bool lan0  = (lane == 0), lan63 = (lane == 63);
    const bool core  = (rb >= (di >> 2)) && (rb < (di >> 2) + TI / 4)
                    && (cb >= (dj >> 2)) && (cb < (dj >> 2) + TI / 4);
    const int  tmax  = NOUT - base;    // stores only for t <= tmax

    const long gbase = (long)(oi + r0) * GN + oj + c4;

    const int uoff   = (istop ? 0 : (rb * 2 - 1)) * RST + c4;
    const int doff   = (isbot ? (NRB * 2 - 1) : (rb * 2 + 2)) * RST + c4;
    const int w0off  = (rb * 2) * RST + c4;
    const int w3off  = (rb * 2 + 1) * RST + c4;
    const int sloff  = AXB + cb * RST + rb * 4;              // lane0 read
    const int wsloff = AXB + (cb + 1) * RST + rb * 4;        // lane63 write
    const int sroff  = AXB + AXS + (cb + 1) * RST + rb * 4;  // lane63 read
    const int wsroff = AXB + AXS + cb * RST + rb * 4;        // lane0 write

    const f2 m4 = {-4.0f, -4.0f};

    // Coefficients as pairs; k2 PRE-NEGATED (exact sign flip).
    f2 a2A[4], a2B[4], nk2A[4], nk2B[4];
    if (USE_WS) {
        #pragma unroll
        for (int q = 0; q < 4; ++q) {
            float4 a = *(const float4*)(Aarg + gbase + q * GN);
            float4 k = *(const float4*)(Karg + gbase + q * GN);
            a2A[q]  = (f2){ a.x,  a.y };
            a2B[q]  = (f2){ a.z,  a.w };
            nk2A[q] = (f2){ -k.x, -k.y };
            nk2B[q] = (f2){ -k.z, -k.w };
        }
    } else {
        #pragma unroll
        for (int q = 0; q < 4; ++q) {
            int gi = oi + r0 + q;
            int ci = gi < 1 ? 1 : (gi > GN - 2 ? GN - 2 : gi);
            int i0, i1; float wi;
            coord16(ci, i0, i1, wi);
            float av[4], kv[4];
            #pragma unroll
            for (int u = 0; u < 4; ++u) {
                int gj = oj + c4 + u;
                int cj = gj < 1 ? 1 : (gj > GN - 2 ? GN - 2 : gj);
                int j0, j1; float wj;
                coord16(cj, j0, j1, wj);
                av[u] = bilin16(Aarg, i0, i1, wi, j0, j1, wj) * 0.1046529f;
                kv[u] = bilin16(Karg, i0, i1, wi, j0, j1, wj) * 5.115e-5f;
            }
            a2A[q]  = (f2){ av[0],  av[1] };
            a2B[q]  = (f2){ av[2],  av[3] };
            nk2A[q] = (f2){ -kv[0], -kv[1] };
            nk2B[q] = (f2){ -kv[2], -kv[3] };
        }
    }

    // All-raw seed: LDS boundary rows + (lane-gated) aux + register carry.
    f2 vA0, vB0, vA1, vB1, vA2, vB2, vA3, vB3;
    {
        float4 ld0 = *(const float4*)(srcp + gbase);
        float4 ld1 = *(const float4*)(srcp + gbase + GN);
        float4 ld2 = *(const float4*)(srcp + gbase + 2 * GN);
        float4 ld3 = *(const float4*)(srcp + gbase + 3 * GN);
        *(float4*)&lds[0][w0off] = ld0;
        *(float4*)&lds[0][w3off] = ld3;
        if (lan63) *(float4*)&lds[0][wsloff] = make_float4(ld0.w, ld1.w, ld2.w, ld3.w);
        if (lan0)  *(float4*)&lds[0][wsroff] = make_float4(ld0.x, ld1.x, ld2.x, ld3.x);
        vA0 = (f2){ld0.x, ld0.y}; vB0 = (f2){ld0.z, ld0.w};
        vA1 = (f2){ld1.x, ld1.y}; vB1 = (f2){ld1.z, ld1.w};
        vA2 = (f2){ld2.x, ld2.y}; vB2 = (f2){ld2.z, ld2.w};
        vA3 = (f2){ld3.x, ld3.y}; vB3 = (f2){ld3.z, ld3.w};
    }
    __syncthreads();

    const int ahi_s = di + TI - 1;     // core row range [di, ahi_s]

    #pragma unroll
    for (int t = 1; t <= KH; ++t) {
        const float* cur = (t & 1) ? &lds[0][0] : &lds[1][0];
        float*       nxt = (t & 1) ? &lds[1][0] : &lds[0][0];

        const int marg = KH - t;                     // compile-time
        int alo = di - marg;      if (alo < 0) alo = 0;
        int ahi = ahi_s + marg;   if (ahi > SZI - 1) ahi = SZI - 1;

        if (r0 + 3 >= alo && r0 <= ahi) {
            float4 U  = *(const float4*)(cur + uoff);
            float4 D  = *(const float4*)(cur + doff);

            // Horizontal exchange: DPP wave shifts from the carry registers.
            float SL0 = dpp_shr1(vB0.y), SL1 = dpp_shr1(vB1.y);
            float SL2 = dpp_shr1(vB2.y), SL3 = dpp_shr1(vB3.y);
            float SR0 = dpp_shl1(vA0.x), SR1 = dpp_shl1(vA1.x);
            float SR2 = dpp_shl1(vA2.x), SR3 = dpp_shl1(vA3.x);
            if (lan0) {            // wave-boundary: left value from aux
                float4 ax = *(const float4*)(cur + sloff);
                SL0 = ax.x; SL1 = ax.y; SL2 = ax.z; SL3 = ax.w;
            }
            if (lan63) {           // wave-boundary: right value from aux
                float4 ax = *(const float4*)(cur + sroff);
                SR0 = ax.x; SR1 = ax.y; SR2 = ax.z; SR3 = ax.w;
            }

            f2 uA = (f2){U.x, U.y}, uB = (f2){U.z, U.w};
            f2 dA = (f2){D.x, D.y}, dB = (f2){D.z, D.w};

            f2 LA, M, RB, nA0, nB0, nA1, nB1, nA2, nB2, nA3, nB3;
            // Row 0  (up = LDS U, down = old row1)
            LA = (f2){SL0, vA0.x}; M = (f2){vA0.y, vB0.x}; RB = (f2){vB0.y, SR0};
            nA0 = pairv(vA0, LA, M, uA, vA1, a2A[0], nk2A[0], m4);
            nB0 = pairv(vB0, M, RB, uB, vB1, a2B[0], nk2B[0], m4);
            // Row 1
            LA = (f2){SL1, vA1.x}; M = (f2){vA1.y, vB1.x}; RB = (f2){vB1.y, SR1};
            nA1 = pairv(vA1, LA, M, vA0, vA2, a2A[1], nk2A[1], m4);
            nB1 = pairv(vB1, M, RB, vB0, vB2, a2B[1], nk2B[1], m4);
            // Row 2
            LA = (f2){SL2, vA2.x}; M = (f2){vA2.y, vB2.x}; RB = (f2){vB2.y, SR2};
            nA2 = pairv(vA2, LA, M, vA1, vA3, a2A[2], nk2A[2], m4);
            nB2 = pairv(vB2, M, RB, vB1, vB3, a2B[2], nk2B[2], m4);
            // Row 3  (down = LDS D)
            LA = (f2){SL3, vA3.x}; M = (f2){vA3.y, vB3.x}; RB = (f2){vB3.y, SR3};
            nA3 = pairv(vA3, LA, M, vA2, dA, a2A[3], nk2A[3], m4);
            nB3 = pairv(vB3, M, RB, vB2, dB, a2B[3], nk2B[3], m4);

            if (istop) { nA0 = nA1; nB0 = nB1; }     // row replicas first
            if (isbot) { nA3 = nA2; nB3 = nB2; }
            if (isl) { nA0.x = nA0.y; nA1.x = nA1.y; // column replicas
                       nA2.x = nA2.y; nA3.x = nA3.y; }
            if (isr) { nB0.y = nB0.x; nB1.y = nB1.x;
                       nB2.y = nB2.x; nB3.y = nB3.x; }

            // Merged b128 LDS writes
            *(float4*)(nxt + w0off) = make_float4(nA0.x, nA0.y, nB0.x, nB0.y);
            *(float4*)(nxt + w3off) = make_float4(nA3.x, nA3.y, nB3.x, nB3.y);
            if (lan63) *(float4*)(nxt + wsloff) = make_float4(nB0.y, nB1.y, nB2.y, nB3.y);
            if (lan0)  *(float4*)(nxt + wsroff) = make_float4(nA0.x, nA1.x, nA2.x, nA3.x);

            if (core && t <= tmax) {
                float* slab = out + (long)(base + t - 1) * GNN;
                *(float4*)(slab + gbase)          = make_float4(nA0.x, nA0.y, nB0.x, nB0.y);
                *(float4*)(slab + gbase + GN)     = make_float4(nA1.x, nA1.y, nB1.x, nB1.y);
                *(float4*)(slab + gbase + 2 * GN) = make_float4(nA2.x, nA2.y, nB2.x, nB2.y);
                *(float4*)(slab + gbase + 3 * GN) = make_float4(nA3.x, nA3.y, nB3.x, nB3.y);
            }
            vA0 = nA0; vB0 = nB0; vA1 = nA1; vB1 = nB1;
            vA2 = nA2; vB2 = nB2; vA3 = nA3; vB3 = nB3;
        }
        lds_barrier();   // LDS-only wait; global stores drain in background
    }
}

extern "C" void kernel_launch(void* const* d_in, const int* in_sizes, int n_in,
                              void* d_out, int out_size, void* d_ws, size_t ws_size,
                              hipStream_t stream) {
    const float* u0    = (const float*)d_in[0];
    const float* alpha = (const float*)d_in[1];
    const float* kappa = (const float*)d_in[2];
    float* out = (float*)d_out;

    dim3 grd(GN / TI, GN / TI, 1);   // 16x16 = 256 blocks = 1/CU
    dim3 blk(NTHR, 1, 1);

    bool use_ws = ws_size >= (size_t)2 * GNN * sizeof(float);

    if (use_ws) {
        float* a2map = (float*)d_ws;
        float* k2map = a2map + GNN;
        resize_maps_kernel<<<(GNN + 255) / 256, 256, 0, stream>>>(alpha, kappa, a2map, k2map);
        for (int b = 0; b < NOUT; b += KH) {
            const float* src = (b == 0) ? u0 : out + (long)(b - 1) * GNN;
            fused_steps_kernel<true><<<grd, blk, 0, stream>>>(src, a2map, k2map, out, b);
        }
    } else {
        for (int b = 0; b < NOUT; b += KH) {
            const float* src = (b == 0) ? u0 : out + (long)(b - 1) * GNN;
            fused_steps_kernel<false><<<grd, blk, 0, stream>>>(src, alpha, kappa, out, b);
        }
    }
}

// Round 15
// 186.910 us; speedup vs baseline: 1.0209x; 1.0209x over previous
//
#include <hip/hip_runtime.h>

#define GN   1024
#define GNN  (GN * GN)
#define GP   16
#define NOUT 127          // ys[1:] = T_1 .. T_127
#define TI   64           // output tile side
#define KH   16           // halo depth = fused steps per launch
#define SZI  96           // region side (TI + 2*KH)
#define NRB  24           // row-blocks  (SZI/4)
#define NCB  24           // col-blocks  (SZI/4)
#define NTHR 576          // NRB*NCB threads, 9 waves
#define RST  100          // row-plane stride (floats), 4-aligned
#define AXB  (NRB * 2 * RST)            // aux base within plane = 4800
#define AXS  ((NCB + 1) * RST)          // one aux side = 2500
#define PLN  (AXB + 2 * AXS)            // plane floats = 9800 (39.2 KB)

typedef float f2 __attribute__((ext_vector_type(2)));

// ---- VOP3P packed-f32 primitives (dual IEEE fp32 per instruction; the
// compiler never auto-emits these for scalar HIP code). Pure ops, no
// side effects -> non-volatile asm, scheduler stays free.
__device__ __forceinline__ f2 pk_add(f2 a, f2 b) {
    f2 d; asm("v_pk_add_f32 %0, %1, %2" : "=v"(d) : "v"(a), "v"(b)); return d;
}
__device__ __forceinline__ f2 pk_sub(f2 a, f2 b) {   // a - b
    f2 d; asm("v_pk_add_f32 %0, %1, %2 neg_lo:[0,1] neg_hi:[0,1]"
              : "=v"(d) : "v"(a), "v"(b)); return d;
}
__device__ __forceinline__ f2 pk_mul(f2 a, f2 b) {
    f2 d; asm("v_pk_mul_f32 %0, %1, %2" : "=v"(d) : "v"(a), "v"(b)); return d;
}
__device__ __forceinline__ f2 pk_fma(f2 a, f2 b, f2 c) {   // a*b + c
    f2 d; asm("v_pk_fma_f32 %0, %1, %2, %3"
              : "=v"(d) : "v"(a), "v"(b), "v"(c)); return d;
}

// Exact fp32 constants: DT/dx^2 = 1e-7*1023^2 = 0.1046529, DT/(2dx) = 5.115e-5

__device__ __forceinline__ void coord16(int t, int& c0, int& c1, float& w) {
    double c = (double)t * (15.0 / 1023.0);
    c0 = (int)c;
    c1 = c0 + 1 > 15 ? 15 : c0 + 1;
    w  = (float)(c - (double)c0);
}

__device__ __forceinline__ float bilin16(const float* __restrict__ m,
                                         int i0, int i1, float wi,
                                         int j0, int j1, float wj) {
    float m00 = m[i0 * GP + j0];
    float m10 = m[i1 * GP + j0];
    float m01 = m[i0 * GP + j1];
    float m11 = m[i1 * GP + j1];
    float r0 = m00 * (1.0f - wi) + m10 * wi;
    float r1 = m01 * (1.0f - wi) + m11 * wi;
    return r0 * (1.0f - wj) + r1 * wj;
}

// Packed pair stencil — bitwise identical to the scalar cellv:
//   s = (D-U)+(R-L); lap = fma(-4,C,(U+D)+(L+R));
//   val = fma(a2, lap, fma(-k2, C*s, C))   (k2 pre-negated at setup)
__device__ __forceinline__ f2 pairv(f2 C, f2 L, f2 R, f2 U, f2 D,
                                    f2 a2, f2 nk2, f2 m4) {
    f2 s   = pk_add(pk_sub(D, U), pk_sub(R, L));
    f2 lap = pk_fma(m4, C, pk_add(pk_add(U, D), pk_add(L, R)));
    f2 cs  = pk_mul(C, s);
    return pk_fma(a2, lap, pk_fma(nk2, cs, C));
}

// LDS barrier (memory clobber; r11 proved vmcnt-drain is perf-neutral here).
__device__ __forceinline__ void lds_barrier() {
    __builtin_amdgcn_sched_barrier(0);
    asm volatile("s_waitcnt lgkmcnt(0)" ::: "memory");
    __builtin_amdgcn_s_barrier();
    __builtin_amdgcn_sched_barrier(0);
}

// Clamp-baked, pre-scaled coefficient maps.
__global__ __launch_bounds__(256)
void resize_maps_kernel(const float* __restrict__ alpha,
                        const float* __restrict__ kappa,
                        float* __restrict__ a2map,
                        float* __restrict__ k2map) {
    int idx = blockIdx.x * 256 + threadIdx.x;
    if (idx >= GNN) return;
    int i = idx >> 10;
    int j = idx & (GN - 1);
    int ci = i < 1 ? 1 : (i > GN - 2 ? GN - 2 : i);
    int cj = j < 1 ? 1 : (j > GN - 2 ? GN - 2 : j);
    int i0, i1, j0, j1; float wi, wj;
    coord16(ci, i0, i1, wi);
    coord16(cj, j0, j1, wj);
    a2map[idx] = bilin16(alpha, i0, i1, wi, j0, j1, wj) * 0.1046529f;
    k2map[idx] = bilin16(kappa, i0, i1, wi, j0, j1, wj) * 5.115e-5f;
}

// Temporal-blocked stepper (verified structure rounds 4-12) with the stencil
// re-expressed in packed-f32 pairs: row of 4 cells = pairs A=(c0,c1),
// B=(c2,c3); vertical operands pair for free; horizontal shifted pairs
// LA=(sl,c0), M=(c1,c2), RB=(c3,sr) are built with movs. Replica-copy edge
// handling, all-raw seed, full 16-step unroll, row-window skip unchanged.
template <bool USE_WS>
__global__ __launch_bounds__(NTHR)
void fused_steps_kernel(const float* __restrict__ srcp,
                        const float* __restrict__ Aarg,   // a2map or alpha
                        const float* __restrict__ Karg,   // k2map or kappa
                        float* __restrict__ out,
                        int base)
{
    __shared__ float lds[2][PLN];   // 2 x 39.2 KB

    const int tid = threadIdx.x;
    const int rb  = tid / NCB;
    const int cb  = tid - rb * NCB;
    const int r0  = rb * 4;
    const int c4  = cb * 4;

    const int gi0 = blockIdx.y * TI;
    const int gj0 = blockIdx.x * TI;
    int oi = gi0 - KH; oi = oi < 0 ? 0 : (oi > GN - SZI ? GN - SZI : oi);
    int oj = gj0 - KH; oj = oj < 0 ? 0 : (oj > GN - SZI ? GN - SZI : oj);
    const int di = gi0 - oi;           // 0, 16, or 32
    const int dj = gj0 - oj;

    const bool istop = (rb == 0), isbot = (rb == NRB - 1);
    const bool isl   = (cb == 0), isr   = (cb == NCB - 1);
    const bool core  = (rb >= (di >> 2)) && (rb < (di >> 2) + TI / 4)
                    && (cb >= (dj >> 2)) && (cb < (dj >> 2) + TI / 4);
    const int  tmax  = NOUT - base;    // stores only for t <= tmax

    const long gbase = (long)(oi + r0) * GN + oj + c4;

    const int uoff   = (istop ? 0 : (rb * 2 - 1)) * RST + c4;
    const int doff   = (isbot ? (NRB * 2 - 1) : (rb * 2 + 2)) * RST + c4;
    const int w0off  = (rb * 2) * RST + c4;
    const int w3off  = (rb * 2 + 1) * RST + c4;
    const int sloff  = AXB + cb * RST + rb * 4;
    const int wsloff = AXB + (cb + 1) * RST + rb * 4;
    const int sroff  = AXB + AXS + (cb + 1) * RST + rb * 4;
    const int wsroff = AXB + AXS + cb * RST + rb * 4;

    const f2 m4 = {-4.0f, -4.0f};

    // Coefficients as pairs; k2 PRE-NEGATED (exact sign flip).
    f2 a2A[4], a2B[4], nk2A[4], nk2B[4];
    if (USE_WS) {
        #pragma unroll
        for (int q = 0; q < 4; ++q) {
            float4 a = *(const float4*)(Aarg + gbase + q * GN);
            float4 k = *(const float4*)(Karg + gbase + q * GN);
            a2A[q]  = (f2){ a.x,  a.y };
            a2B[q]  = (f2){ a.z,  a.w };
            nk2A[q] = (f2){ -k.x, -k.y };
            nk2B[q] = (f2){ -k.z, -k.w };
        }
    } else {
        #pragma unroll
        for (int q = 0; q < 4; ++q) {
            int gi = oi + r0 + q;
            int ci = gi < 1 ? 1 : (gi > GN - 2 ? GN - 2 : gi);
            int i0, i1; float wi;
            coord16(ci, i0, i1, wi);
            float av[4], kv[4];
            #pragma unroll
            for (int u = 0; u < 4; ++u) {
                int gj = oj + c4 + u;
                int cj = gj < 1 ? 1 : (gj > GN - 2 ? GN - 2 : gj);
                int j0, j1; float wj;
                coord16(cj, j0, j1, wj);
                av[u] = bilin16(Aarg, i0, i1, wi, j0, j1, wj) * 0.1046529f;
                kv[u] = bilin16(Karg, i0, i1, wi, j0, j1, wj) * 5.115e-5f;
            }
            a2A[q]  = (f2){ av[0],  av[1] };
            a2B[q]  = (f2){ av[2],  av[3] };
            nk2A[q] = (f2){ -kv[0], -kv[1] };
            nk2B[q] = (f2){ -kv[2], -kv[3] };
        }
    }

    // All-raw seed: LDS boundary rows + aux columns + register carry (pairs).
    f2 vA0, vB0, vA1, vB1, vA2, vB2, vA3, vB3;
    {
        float4 ld0 = *(const float4*)(srcp + gbase);
        float4 ld1 = *(const float4*)(srcp + gbase + GN);
        float4 ld2 = *(const float4*)(srcp + gbase + 2 * GN);
        float4 ld3 = *(const float4*)(srcp + gbase + 3 * GN);
        *(float4*)&lds[0][w0off]  = ld0;
        *(float4*)&lds[0][w3off]  = ld3;
        *(float4*)&lds[0][wsloff] = make_float4(ld0.w, ld1.w, ld2.w, ld3.w);
        *(float4*)&lds[0][wsroff] = make_float4(ld0.x, ld1.x, ld2.x, ld3.x);
        vA0 = (f2){ld0.x, ld0.y}; vB0 = (f2){ld0.z, ld0.w};
        vA1 = (f2){ld1.x, ld1.y}; vB1 = (f2){ld1.z, ld1.w};
        vA2 = (f2){ld2.x, ld2.y}; vB2 = (f2){ld2.z, ld2.w};
        vA3 = (f2){ld3.x, ld3.y}; vB3 = (f2){ld3.z, ld3.w};
    }
    __syncthreads();

    const int ahi_s = di + TI - 1;     // core row range [di, ahi_s]

    #pragma unroll
    for (int t = 1; t <= KH; ++t) {
        const float* cur = (t & 1) ? &lds[0][0] : &lds[1][0];
        float*       nxt = (t & 1) ? &lds[1][0] : &lds[0][0];

        const int marg = KH - t;                     // compile-time
        int alo = di - marg;      if (alo < 0) alo = 0;
        int ahi = ahi_s + marg;   if (ahi > SZI - 1) ahi = SZI - 1;

        if (r0 + 3 >= alo && r0 <= ahi) {
            float4 U  = *(const float4*)(cur + uoff);
            float4 D  = *(const float4*)(cur + doff);
            float4 SL = *(const float4*)(cur + sloff);
            float4 SR = *(const float4*)(cur + sroff);

            f2 uA = (f2){U.x, U.y}, uB = (f2){U.z, U.w};
            f2 dA = (f2){D.x, D.y}, dB = (f2){D.z, D.w};

            // Row 0  (up = LDS U, down = old row1)
            f2 LA, M, RB, nA0, nB0, nA1, nB1, nA2, nB2, nA3, nB3;
            LA = (f2){SL.x, vA0.x}; M = (f2){vA0.y, vB0.x}; RB = (f2){vB0.y, SR.x};
            nA0 = pairv(vA0, LA, M, uA, vA1, a2A[0], nk2A[0], m4);
            nB0 = pairv(vB0, M, RB, uB, vB1, a2B[0], nk2B[0], m4);
            // Row 1  (up = old row0, down = old row2)
            LA = (f2){SL.y, vA1.x}; M = (f2){vA1.y, vB1.x}; RB = (f2){vB1.y, SR.y};
            nA1 = pairv(vA1, LA, M, vA0, vA2, a2A[1], nk2A[1], m4);
            nB1 = pairv(vB1, M, RB, vB0, vB2, a2B[1], nk2B[1], m4);
            // Row 2  (up = old row1, down = old row3)
            LA = (f2){SL.z, vA2.x}; M = (f2){vA2.y, vB2.x}; RB = (f2){vB2.y, SR.z};
            nA2 = pairv(vA2, LA, M, vA1, vA3, a2A[2], nk2A[2], m4);
            nB2 = pairv(vB2, M, RB, vB1, vB3, a2B[2], nk2B[2], m4);
            // Row 3  (up = old row2, down = LDS D)
            LA = (f2){SL.w, vA3.x}; M = (f2){vA3.y, vB3.x}; RB = (f2){vB3.y, SR.w};
            nA3 = pairv(vA3, LA, M, vA2, dA, a2A[3], nk2A[3], m4);
            nB3 = pairv(vB3, M, RB, vB2, dB, a2B[3], nk2B[3], m4);

            if (istop) { nA0 = nA1; nB0 = nB1; }     // row replicas first
            if (isbot) { nA3 = nA2; nB3 = nB2; }
            if (isl) { nA0.x = nA0.y; nA1.x = nA1.y; // column replicas
                       nA2.x = nA2.y; nA3.x = nA3.y; }
            if (isr) { nB0.y = nB0.x; nB1.y = nB1.x;
                       nB2.y = nB2.x; nB3.y = nB3.x; }

            // LDS plane writes (pair-granular; compiler may merge to b128)
            *(f2*)(nxt + w0off)     = nA0;  *(f2*)(nxt + w0off + 2) = nB0;
            *(f2*)(nxt + w3off)     = nA3;  *(f2*)(nxt + w3off + 2) = nB3;
            *(f2*)(nxt + wsloff)     = (f2){nB0.y, nB1.y};
            *(f2*)(nxt + wsloff + 2) = (f2){nB2.y, nB3.y};
            *(f2*)(nxt + wsroff)     = (f2){nA0.x, nA1.x};
            *(f2*)(nxt + wsroff + 2) = (f2){nA2.x, nA3.x};

            if (core && t <= tmax) {
                float* slab = out + (long)(base + t - 1) * GNN;
                *(f2*)(slab + gbase)              = nA0;
                *(f2*)(slab + gbase + 2)          = nB0;
                *(f2*)(slab + gbase + GN)         = nA1;
                *(f2*)(slab + gbase + GN + 2)     = nB1;
                *(f2*)(slab + gbase + 2 * GN)     = nA2;
                *(f2*)(slab + gbase + 2 * GN + 2) = nB2;
                *(f2*)(slab + gbase + 3 * GN)     = nA3;
                *(f2*)(slab + gbase + 3 * GN + 2) = nB3;
            }
            vA0 = nA0; vB0 = nB0; vA1 = nA1; vB1 = nB1;
            vA2 = nA2; vB2 = nB2; vA3 = nA3; vB3 = nB3;
        }
        lds_barrier();   // LDS-only wait; global stores drain in background
    }
}

extern "C" void kernel_launch(void* const* d_in, const int* in_sizes, int n_in,
                              void* d_out, int out_size, void* d_ws, size_t ws_size,
                              hipStream_t stream) {
    const float* u0    = (const float*)d_in[0];
    const float* alpha = (const float*)d_in[1];
    const float* kappa = (const float*)d_in[2];
    float* out = (float*)d_out;

    dim3 grd(GN / TI, GN / TI, 1);   // 16x16 = 256 blocks = 1/CU
    dim3 blk(NTHR, 1, 1);

    bool use_ws = ws_size >= (size_t)2 * GNN * sizeof(float);

    if (use_ws) {
        float* a2map = (float*)d_ws;
        float* k2map = a2map + GNN;
        resize_maps_kernel<<<(GNN + 255) / 256, 256, 0, stream>>>(alpha, kappa, a2map, k2map);
        for (int b = 0; b < NOUT; b += KH) {
            const float* src = (b == 0) ? u0 : out + (long)(b - 1) * GNN;
            fused_steps_kernel<true><<<grd, blk, 0, stream>>>(src, a2map, k2map, out, b);
        }
    } else {
        for (int b = 0; b < NOUT; b += KH) {
            const float* src = (b == 0) ? u0 : out + (long)(b - 1) * GNN;
            fused_steps_kernel<false><<<grd, blk, 0, stream>>>(src, alpha, kappa, out, b);
        }
    }
}